// Round 8
// baseline (1066.138 us; speedup 1.0000x reference)
//
#include <hip/hip_runtime.h>
#include <hip/hip_bf16.h>

#define TOK   8192      // B*S
#define HD    1024      // H
#define FD    4096      // F
#define NE    8         // E
#define TOPK  2
#define NPAIR (TOK*TOPK)   // 16384, fixed
#define PADR  256          // row padding for tile overrun
#define NSLOT 8            // row-tile slots per expert (loop-strided, any cnt ok)
#define BM    256
#define BN    256

typedef short bf16x8 __attribute__((ext_vector_type(8)));
typedef float f32x4  __attribute__((ext_vector_type(4)));

__device__ inline unsigned short f2bf(float f) {
    unsigned u = __float_as_uint(f);
    unsigned r = (u + 0x7fffu + ((u >> 16) & 1u)) >> 16;
    return (unsigned short)r;
}

// ---------------- transpose + fp32->bf16 convert: in [E][R][C] -> out [E][C][R]
template<int R, int C>
__global__ __launch_bounds__(256) void transpose_cvt_kernel(
    const float* __restrict__ in, short* __restrict__ out)
{
    __shared__ float tile[64][65];
    const int tid = threadIdx.x;
    const int c0 = blockIdx.x * 64, r0 = blockIdx.y * 64, e = blockIdx.z;
    #pragma unroll
    for (int i = 0; i < 16; ++i) {
        int idx = i * 256 + tid;
        int rr = idx >> 6, cc = idx & 63;
        tile[rr][cc] = in[((size_t)e * R + r0 + rr) * C + c0 + cc];
    }
    __syncthreads();
    #pragma unroll
    for (int i = 0; i < 8; ++i) {
        int idx = i * 256 + tid;
        int cc = idx >> 5, rp = idx & 31;
        unsigned lo = f2bf(tile[rp * 2][cc]);
        unsigned hi = f2bf(tile[rp * 2 + 1][cc]);
        unsigned w = lo | (hi << 16);
        *(unsigned*)&out[((size_t)e * C + c0 + cc) * R + r0 + rp * 2] = w;
    }
}

// ---------------- gating: fp64 LN + logits + softmax + top-2 (one wave per token)
__global__ __launch_bounds__(256) void gating_kernel(
    const float* __restrict__ x, const float* __restrict__ gn_g, const float* __restrict__ gn_b,
    const float* __restrict__ gate_w, const float* __restrict__ gate_b,
    int* __restrict__ topk_i, float* __restrict__ topk_w, int* __restrict__ counts)
{
    const int wv = threadIdx.x >> 6, lane = threadIdx.x & 63;
    const int t = blockIdx.x * 4 + wv;
    const float* xr = x + (size_t)t * HD;

    double xs[16];
    #pragma unroll
    for (int i = 0; i < 16; ++i) xs[i] = (double)xr[i * 64 + lane];
    double s = 0.0;
    #pragma unroll
    for (int i = 0; i < 16; ++i) s += xs[i];
    #pragma unroll
    for (int o = 32; o > 0; o >>= 1) s += __shfl_xor(s, o, 64);
    double mean = s * (1.0 / HD);
    double ss = 0.0;
    #pragma unroll
    for (int i = 0; i < 16; ++i) { double d = xs[i] - mean; ss += d * d; }
    #pragma unroll
    for (int o = 32; o > 0; o >>= 1) ss += __shfl_xor(ss, o, 64);
    double inv = 1.0 / sqrt(ss * (1.0 / HD) + 1e-5);

    double ac[NE];
    #pragma unroll
    for (int e = 0; e < NE; ++e) ac[e] = 0.0;
    #pragma unroll
    for (int i = 0; i < 16; ++i) {
        int h = i * 64 + lane;
        double ln = (xs[i] - mean) * inv * (double)gn_g[h] + (double)gn_b[h];
        #pragma unroll
        for (int e = 0; e < NE; ++e) ac[e] += ln * (double)gate_w[h * NE + e];
    }
    #pragma unroll
    for (int e = 0; e < NE; ++e) {
        #pragma unroll
        for (int o = 32; o > 0; o >>= 1) ac[e] += __shfl_xor(ac[e], o, 64);
    }
    if (lane == 0) {
        double lg[NE], p[NE];
        double mx = -1e300;
        #pragma unroll
        for (int e = 0; e < NE; ++e) { lg[e] = ac[e] + (double)gate_b[e]; mx = lg[e] > mx ? lg[e] : mx; }
        double ps = 0.0;
        #pragma unroll
        for (int e = 0; e < NE; ++e) { p[e] = exp(lg[e] - mx); ps += p[e]; }
        #pragma unroll
        for (int e = 0; e < NE; ++e) p[e] /= ps;
        int i0 = 0;
        for (int e = 1; e < NE; ++e) if (p[e] > p[i0]) i0 = e;   // strict > keeps first (jax tie rule)
        int i1 = (i0 == 0) ? 1 : 0;
        for (int e = 0; e < NE; ++e) if (e != i0 && p[e] > p[i1]) i1 = e;
        double den = p[i0] + p[i1] + 1e-9;
        topk_i[t * 2] = i0; topk_i[t * 2 + 1] = i1;
        topk_w[t * 2] = (float)(p[i0] / den);
        topk_w[t * 2 + 1] = (float)(p[i1] / den);
        atomicAdd(&counts[i0], 1);
        atomicAdd(&counts[i1], 1);
    }
}

// ---------------- tiny prefix sum
__global__ void offsets_kernel(const int* __restrict__ counts, int* __restrict__ offs)
{
    if (threadIdx.x == 0) {
        int s = 0;
        for (int e = 0; e < NE; ++e) { offs[e] = s; s += counts[e]; }
        offs[NE] = s;
    }
}

// ---------------- scatter pair ids into expert-grouped list (+ inverse map)
__global__ __launch_bounds__(256) void scatter_kernel(
    const int* __restrict__ topk_i, const int* __restrict__ offs,
    int* __restrict__ cursor, int* __restrict__ pair_tok, int* __restrict__ inv_row)
{
    int idx = blockIdx.x * 256 + threadIdx.x;   // pair id = t*2+k
    if (idx < NPAIR) {
        int e = topk_i[idx];
        int pos = atomicAdd(&cursor[e], 1);
        int dst = offs[e] + pos;
        pair_tok[dst] = idx;
        inv_row[idx] = dst;
    }
}

// ---------------- gather x rows (fp32) -> Xg (bf16, grouped order)
__global__ __launch_bounds__(256) void gather_kernel(
    const float* __restrict__ x, const int* __restrict__ pair_tok, short* __restrict__ Xg)
{
    const int r = blockIdx.x;
    const int t = pair_tok[r] >> 1;
    const int tid = threadIdx.x;
    float4 v = *(const float4*)&x[(size_t)t * HD + tid * 4];
    unsigned w0 = (unsigned)f2bf(v.x) | ((unsigned)f2bf(v.y) << 16);
    unsigned w1 = (unsigned)f2bf(v.z) | ((unsigned)f2bf(v.w) << 16);
    *(uint2*)&Xg[(size_t)r * HD + tid * 4] = make_uint2(w0, w1);
}

// fences
#define FENCE_BAR  asm volatile("s_barrier" ::: "memory")
#define LGKM0      do { asm volatile("s_waitcnt lgkmcnt(0)" ::: "memory"); \
                        __builtin_amdgcn_sched_barrier(0); } while (0)
#define WAITB(n)   do { asm volatile("s_waitcnt vmcnt(" #n ")" ::: "memory"); \
                        FENCE_BAR; __builtin_amdgcn_sched_barrier(0); } while (0)

#define GLOAD(srcp, dstp) __builtin_amdgcn_global_load_lds(                         \
        (const __attribute__((address_space(1))) unsigned*)(srcp),                  \
        (__attribute__((address_space(3))) unsigned*)(dstp), 16, 0, 0)

// ---------------- grouped GEMM, 256x256 tile, BK=64, 2 LDS dbufs (128 KB),
// 8-phase-style schedule: 4 phases/K-tile, 16 MFMA each, staging spread across
// phases with region-freeing; counted vmcnt(7) per K-tile boundary (never 0 in loop).
// A LDS layout: strip s (lds rows 64s..64s+63) holds global rows {32s..32s+31} (h=0)
// and {128+32s..+31} (h=1); granule swizzle g^=(row&7) both sides.
// EPI==1: gelu -> bf16 Hbuf ; EPI==2: +bias -> fp32 Op (both grouped rows)
template<int KDIM, int NDIM, int EPI>
__global__ __launch_bounds__(512, 2) void gemm_kernel(
    const short* __restrict__ A, const short* __restrict__ BT,
    const float* __restrict__ bias, void* __restrict__ outp,
    const int* __restrict__ counts, const int* __restrict__ offs)
{
    // bijective XCD swizzle (nwg % 8 == 0 for all our grids)
    const int nwg = gridDim.x * gridDim.y;
    const int orig = blockIdx.y * gridDim.x + blockIdx.x;
    const int v = (orig & 7) * (nwg >> 3) + (orig >> 3);
    const int bx = v % gridDim.x;             // col tile
    const int by = v / gridDim.x;             // (expert, slot)

    const int tid = threadIdx.x;
    const int e = by >> 3;                    // NSLOT == 8
    const int slot = by & 7;
    const int cnt = counts[e];
    const int colbase = bx * BN;

    // 2 dbufs: A 2 x 256x64, B 2 x 256x64 -> 128 KB
    __shared__ __align__(16) short As[2 * 16384];
    __shared__ __align__(16) short Bs[2 * 16384];

    const int lane = tid & 63;
    const int wv = tid >> 6;                  // 8 waves: 2 M-groups x 4 N-groups
    const int wr = (wv >> 2) * 128, wc = (wv & 3) * 64;
    const int hw = wv >> 2;
    const int l15 = lane & 15, l4 = lane >> 4;

    // ds_read offsets (shorts), ks=0; ks=1 = off ^ 32
    const int swb = (l4 ^ (l15 & 7)) * 8;
    int aoff[8], boff[4];
    #pragma unroll
    for (int m = 0; m < 8; ++m)
        aoff[m] = (64 * (m >> 1) + 32 * hw + 16 * (m & 1) + l15) * 64 + swb;
    #pragma unroll
    for (int n = 0; n < 4; ++n)
        boff[n] = (wc + n * 16 + l15) * 64 + swb;

    // staging constants (per-thread): one 16B gload per region per thread
    const int a_gbase = 128 * (tid >> 8) + ((tid >> 3) & 31);  // + 32*s
    const int b_gbase = (tid >> 3);                            // + 64*q
    const int sw = ((tid & 7) ^ ((tid >> 3) & 7)) << 3;        // pre-swizzled k offset
    const int ldsoff = tid * 8;

    const size_t bbase = (size_t)e * NDIM + colbase;

#define STAGE_A(db, s, kb) GLOAD(A + (size_t)(rowbase + a_gbase + 32 * (s)) * KDIM + (kb) + sw, \
                                 &As[(db) * 16384 + (s) * 4096 + ldsoff])
#define STAGE_B(db, q, kb) GLOAD(BT + (bbase + b_gbase + 64 * (q)) * KDIM + (kb) + sw,          \
                                 &Bs[(db) * 16384 + (q) * 4096 + ldsoff])

    constexpr int NKT = KDIM / 64;

    for (int rt = slot; rt * BM < cnt; rt += NSLOT) {
        const int rowbase = offs[e] + rt * BM;

        // prologue: K-tile 0 complete (8 regions), K-tile 1 partial (7 regions)
        STAGE_A(0, 0, 0);  STAGE_A(0, 1, 0);  STAGE_A(0, 2, 0);  STAGE_A(0, 3, 0);
        STAGE_B(0, 0, 0);  STAGE_B(0, 1, 0);  STAGE_B(0, 2, 0);  STAGE_B(0, 3, 0);
        STAGE_A(1, 0, 64); STAGE_A(1, 1, 64); STAGE_A(1, 2, 64);
        STAGE_B(1, 0, 64); STAGE_B(1, 1, 64); STAGE_B(1, 2, 64); STAGE_B(1, 3, 64);
        WAITB(7);   // K-tile 0's 8 loads done; K-tile 1's 7 in flight

        f32x4 acc[8][4];
        #pragma unroll
        for (int m = 0; m < 8; ++m)
            #pragma unroll
            for (int n = 0; n < 4; ++n)
                acc[m][n] = (f32x4){0.f, 0.f, 0.f, 0.f};

        bf16x8 bk0[4], bk1[4];

#define PHASE_TAIL(m0, m1, aK00, aK01, aK10, aK11) do {                              \
        FENCE_BAR;                                                                   \
        LGKM0;                                                                       \
        __builtin_amdgcn_s_setprio(1);                                               \
        _Pragma("unroll")                                                            \
        for (int n = 0; n < 4; ++n) {                                                \
            acc[m0][n] = __builtin_amdgcn_mfma_f32_16x16x32_bf16(aK00, bk0[n], acc[m0][n], 0, 0, 0); \
            acc[m1][n] = __builtin_amdgcn_mfma_f32_16x16x32_bf16(aK10, bk0[n], acc[m1][n], 0, 0, 0); \
        }                                                                            \
        _Pragma("unroll")                                                            \
        for (int n = 0; n < 4; ++n) {                                                \
            acc[m0][n] = __builtin_amdgcn_mfma_f32_16x16x32_bf16(aK01, bk1[n], acc[m0][n], 0, 0, 0); \
            acc[m1][n] = __builtin_amdgcn_mfma_f32_16x16x32_bf16(aK11, bk1[n], acc[m1][n], 0, 0, 0); \
        }                                                                            \
        __builtin_amdgcn_s_setprio(0);                                               \
        __builtin_amdgcn_sched_barrier(0);                                           \
        FENCE_BAR;                                                                   \
    } while (0)

        for (int kt = 0; kt < NKT; ++kt) {
            const int c = kt & 1, o = c ^ 1;
            const short* asl = &As[c * 16384];
            const short* bsl = &Bs[c * 16384];
            const int kb1 = (kt + 1) * 64, kb2 = (kt + 2) * 64;
            const bool do1 = (kt + 1 < NKT), do2 = (kt + 2 < NKT);

            // ---- phase 0: a m0,m1 + all B reads; stage dbuf-o A-strip3 (kt+1 data)
            {
                bf16x8 a00 = *(const bf16x8*)&asl[aoff[0]];
                bf16x8 a01 = *(const bf16x8*)&asl[aoff[0] ^ 32];
                bf16x8 a10 = *(const bf16x8*)&asl[aoff[1]];
                bf16x8 a11 = *(const bf16x8*)&asl[aoff[1] ^ 32];
                #pragma unroll
                for (int n = 0; n < 4; ++n) {
                    bk0[n] = *(const bf16x8*)&bsl[boff[n]];
                    bk1[n] = *(const bf16x8*)&bsl[boff[n] ^ 32];
                }
                if (do1) STAGE_A(o, 3, kb1);
                PHASE_TAIL(0, 1, a00, a01, a10, a11);
            }
            // ---- phase 1: a m2,m3; stage dbuf-c A-strip0 + B q0,q1 (kt+2 data)
            {
                bf16x8 a00 = *(const bf16x8*)&asl[aoff[2]];
                bf16x8 a01 = *(const bf16x8*)&asl[aoff[2] ^ 32];
                bf16x8 a10 = *(const bf16x8*)&asl[aoff[3]];
                bf16x8 a11 = *(const bf16x8*)&asl[aoff[3] ^ 32];
                if (do2) { STAGE_A(c, 0, kb2); STAGE_B(c, 0, kb2); STAGE_B(c, 1, kb2); }
                PHASE_TAIL(2, 3, a00, a01, a10, a11);
            }
            // ---- phase 2: a m4,m5; stage dbuf-c A-strip1 + B q2,q3
            {
                bf16x8 a00 = *(const bf16x8*)&asl[aoff[4]];
                bf16x8 a01 = *(const bf16x8*)&asl[aoff[4] ^ 32];
                bf16x8 a10 = *(const bf16x8*)&asl[aoff[5]];
                bf16x8 a11 = *(const bf16x8*)&asl[aoff[5] ^ 32];
                if (do2) { STAGE_A(c, 1, kb2); STAGE_B(c, 2, kb2); STAGE_B(c, 3, kb2); }
                PHASE_TAIL(4, 5, a00, a01, a10, a11);
            }
            // ---- phase 3: a m6,m7; stage dbuf-c A-strip2
            {
                bf16x8 a00 = *(const bf16x8*)&asl[aoff[6]];
                bf16x8 a01 = *(const bf16x8*)&asl[aoff[6] ^ 32];
                bf16x8 a10 = *(const bf16x8*)&asl[aoff[7]];
                bf16x8 a11 = *(const bf16x8*)&asl[aoff[7] ^ 32];
                if (do2) STAGE_A(c, 2, kb2);
                PHASE_TAIL(6, 7, a00, a01, a10, a11);
            }
            // ---- K-tile boundary: next tile's 8 loads must be done; keep newest 7 in flight
            if (kt < NKT - 1) {
                if (kt == NKT - 2) WAITB(0); else WAITB(7);
            }
        }
#undef PHASE_TAIL

        const int rmax = cnt - rt * BM;   // valid rows in this tile (tail tiles < BM)

        if (EPI == 1) {
            short* Hb = (short*)outp;
            #pragma unroll
            for (int n = 0; n < 4; ++n) {
                int col = colbase + wc + n * 16 + l15;
                float bv = bias[e * NDIM + col];
                #pragma unroll
                for (int m = 0; m < 8; ++m) {
                    int r0l = wr + m * 16 + l4 * 4;
                    #pragma unroll
                    for (int r = 0; r < 4; ++r) {
                        int rl = r0l + r;
                        if (rl < rmax) {   // guard: do NOT clobber next expert's rows
                            float vv = acc[m][n][r] + bv;
                            vv = 0.5f * vv * (1.0f + erff(vv * 0.70710678118654752f));
                            Hb[(size_t)(rowbase + rl) * NDIM + col] = (short)f2bf(vv);
                        }
                    }
                }
            }
        } else {
            float* Op = (float*)outp;      // grouped-row order (coalesced tiles)
            #pragma unroll
            for (int n = 0; n < 4; ++n) {
                int col = colbase + wc + n * 16 + l15;
                float bv = bias[e * NDIM + col];
                #pragma unroll
                for (int m = 0; m < 8; ++m) {
                    int r0l = wr + m * 16 + l4 * 4;
                    #pragma unroll
                    for (int r = 0; r < 4; ++r) {
                        int rl = r0l + r;
                        if (rl < rmax)
                            Op[(size_t)(rowbase + rl) * NDIM + col] = acc[m][n][r] + bv;
                    }
                }
            }
        }
    }
#undef STAGE_A
#undef STAGE_B
}

// ---------------- residual + LN + weighted top-k combine (Op in grouped order)
__device__ inline float block_sum256(float v, volatile float* red, int tid)
{
    #pragma unroll
    for (int o = 32; o > 0; o >>= 1) v += __shfl_xor(v, o, 64);
    __syncthreads();
    if ((tid & 63) == 0) red[tid >> 6] = v;
    __syncthreads();
    return red[0] + red[1] + red[2] + red[3];
}

__global__ __launch_bounds__(256) void ln_combine_kernel(
    const float* __restrict__ Op, const float* __restrict__ x,
    const int* __restrict__ topk_i, const float* __restrict__ topk_w,
    const int* __restrict__ inv_row,
    const float* __restrict__ ln_g, const float* __restrict__ ln_b,
    float* __restrict__ y)
{
    __shared__ float red[4];
    const int t = blockIdx.x, tid = threadIdx.x;
    const float4 xr = *(const float4*)&x[(size_t)t * HD + tid * 4];
    float a0 = 0.f, a1 = 0.f, a2 = 0.f, a3 = 0.f;
    #pragma unroll
    for (int k = 0; k < TOPK; ++k) {
        int e = topk_i[t * 2 + k];
        float w = topk_w[t * 2 + k];
        int grow = inv_row[t * 2 + k];
        const float4 o = *(const float4*)&Op[(size_t)grow * HD + tid * 4];
        float v0 = o.x + xr.x, v1 = o.y + xr.y, v2 = o.z + xr.z, v3 = o.w + xr.w;
        float s = block_sum256(v0 + v1 + v2 + v3, red, tid);
        float m = s * (1.0f / HD);
        float d0 = v0 - m, d1 = v1 - m, d2 = v2 - m, d3 = v3 - m;
        float ssq = block_sum256(d0 * d0 + d1 * d1 + d2 * d2 + d3 * d3, red, tid);
        float inv = 1.0f / sqrtf(ssq * (1.0f / HD) + 1e-5f);
        int base = e * HD + tid * 4;
        const float4 g = *(const float4*)&ln_g[base];
        const float4 bb = *(const float4*)&ln_b[base];
        a0 += w * (d0 * inv * g.x + bb.x);
        a1 += w * (d1 * inv * g.y + bb.y);
        a2 += w * (d2 * inv * g.z + bb.z);
        a3 += w * (d3 * inv * g.w + bb.w);
    }
    *(float4*)&y[(size_t)t * HD + tid * 4] = make_float4(a0, a1, a2, a3);
}

__global__ void zero_out_kernel(float* __restrict__ y, int n)
{
    int i = blockIdx.x * 256 + threadIdx.x;
    if (i < n) y[i] = 0.f;
}

extern "C" void kernel_launch(void* const* d_in, const int* in_sizes, int n_in,
                              void* d_out, int out_size, void* d_ws, size_t ws_size,
                              hipStream_t stream)
{
    const float* x      = (const float*)d_in[0];
    const float* W1     = (const float*)d_in[1];
    const float* b1     = (const float*)d_in[2];
    const float* W2     = (const float*)d_in[3];
    const float* b2     = (const float*)d_in[4];
    const float* ln_g   = (const float*)d_in[5];
    const float* ln_b   = (const float*)d_in[6];
    const float* gn_g   = (const float*)d_in[7];
    const float* gn_b   = (const float*)d_in[8];
    const float* gate_w = (const float*)d_in[9];
    const float* gate_b = (const float*)d_in[10];
    float* y = (float*)d_out;

    char* ws = (char*)d_ws;
    size_t off = 0;
    auto take = [&](size_t b) -> char* {
        char* p = ws + off;
        off = (off + b + 255) & ~(size_t)255;
        return p;
    };
    short* W1T     = (short*)take((size_t)NE * FD * HD * 2);       // [E][F][H] bf16
    short* W2T     = (short*)take((size_t)NE * HD * FD * 2);       // [E][H][F] bf16
    short* Xg      = (short*)take((size_t)(NPAIR + PADR) * HD * 2);
    short* Hb      = (short*)take((size_t)(NPAIR + PADR) * FD * 2);
    float* Op      = (float*)take((size_t)NPAIR * HD * 4);         // grouped rows
    int*   topk_i  = (int*)take(NPAIR * 4);
    float* topk_w  = (float*)take(NPAIR * 4);
    int*   cnts    = (int*)take(64);            // 8 counts + 8 cursor
    int*   cursor  = cnts + 8;
    int*   offs    = (int*)take(64);
    int*   pair_tok= (int*)take((size_t)(NPAIR + PADR) * 4);
    int*   inv_row = (int*)take((size_t)NPAIR * 4);

    if (ws_size < off) {   // workspace too small: emit zeros so failure mode is diagnosable
        zero_out_kernel<<<(out_size + 255) / 256, 256, 0, stream>>>(y, out_size);
        return;
    }

    hipMemsetAsync(cnts, 0, 64, stream);

    transpose_cvt_kernel<HD, FD><<<dim3(FD / 64, HD / 64, NE), 256, 0, stream>>>(W1, W1T);
    transpose_cvt_kernel<FD, HD><<<dim3(HD / 64, FD / 64, NE), 256, 0, stream>>>(W2, W2T);

    gating_kernel<<<TOK / 4, 256, 0, stream>>>(x, gn_g, gn_b, gate_w, gate_b, topk_i, topk_w, cnts);
    offsets_kernel<<<1, 64, 0, stream>>>(cnts, offs);
    scatter_kernel<<<NPAIR / 256, 256, 0, stream>>>(topk_i, offs, cursor, pair_tok, inv_row);
    gather_kernel<<<NPAIR, 256, 0, stream>>>(x, pair_tok, Xg);

    // GEMM1: [pairs x HD] @ W1T -> gelu -> Hb   (16 col tiles x 64 (e,slot))
    gemm_kernel<HD, FD, 1><<<dim3(FD / BN, NE * NSLOT), 512, 0, stream>>>(
        Xg, W1T, b1, (void*)Hb, cnts, offs);
    // GEMM2: [pairs x FD] @ W2T -> +b2 -> Op (grouped)   (4 col tiles x 64)
    gemm_kernel<FD, HD, 2><<<dim3(HD / BN, NE * NSLOT), 512, 0, stream>>>(
        Hb, W2T, b2, (void*)Op, cnts, offs);

    ln_combine_kernel<<<TOK, 256, 0, stream>>>(Op, x, topk_i, topk_w, inv_row, ln_g, ln_b, y);
}

// Round 9
// 1048.472 us; speedup vs baseline: 1.0168x; 1.0168x over previous
//
#include <hip/hip_runtime.h>
#include <hip/hip_bf16.h>

#define TOK   8192      // B*S
#define HD    1024      // H
#define FD    4096      // F
#define NE    8         // E
#define TOPK  2
#define NPAIR (TOK*TOPK)   // 16384, fixed
#define PADR  256          // row padding for tile overrun
#define NSLOT 8            // row-tile slots per expert
#define BM    256
#define BN    256
#define BK    64

typedef short bf16x8 __attribute__((ext_vector_type(8)));
typedef float f32x4  __attribute__((ext_vector_type(4)));

__device__ inline unsigned short f2bf(float f) {
    unsigned u = __float_as_uint(f);
    unsigned r = (u + 0x7fffu + ((u >> 16) & 1u)) >> 16;
    return (unsigned short)r;
}

// ---------------- transpose + fp32->bf16 convert: in [E][R][C] -> out [E][C][R]
template<int R, int C>
__global__ __launch_bounds__(256) void transpose_cvt_kernel(
    const float* __restrict__ in, short* __restrict__ out)
{
    __shared__ float tile[64][65];
    const int tid = threadIdx.x;
    const int c0 = blockIdx.x * 64, r0 = blockIdx.y * 64, e = blockIdx.z;
    #pragma unroll
    for (int i = 0; i < 4; ++i) {
        int idx = i * 1024 + tid * 4;
        int rr = idx >> 6, cc = idx & 63;
        float4 v = *(const float4*)&in[((size_t)e * R + r0 + rr) * C + c0 + cc];
        tile[rr][cc] = v.x; tile[rr][cc + 1] = v.y;
        tile[rr][cc + 2] = v.z; tile[rr][cc + 3] = v.w;
    }
    __syncthreads();
    #pragma unroll
    for (int i = 0; i < 8; ++i) {
        int idx = i * 256 + tid;
        int cc = idx >> 5, rp = idx & 31;
        unsigned lo = f2bf(tile[rp * 2][cc]);
        unsigned hi = f2bf(tile[rp * 2 + 1][cc]);
        unsigned w = lo | (hi << 16);
        *(unsigned*)&out[((size_t)e * C + c0 + cc) * R + r0 + rp * 2] = w;
    }
}

// ---------------- gating: fp64 LN + logits + softmax + top-2 (one wave per token)
__global__ __launch_bounds__(256) void gating_kernel(
    const float* __restrict__ x, const float* __restrict__ gn_g, const float* __restrict__ gn_b,
    const float* __restrict__ gate_w, const float* __restrict__ gate_b,
    int* __restrict__ topk_i, float* __restrict__ topk_w, int* __restrict__ counts)
{
    const int wv = threadIdx.x >> 6, lane = threadIdx.x & 63;
    const int t = blockIdx.x * 4 + wv;
    const float* xr = x + (size_t)t * HD;

    double xs[16];
    #pragma unroll
    for (int i = 0; i < 16; ++i) xs[i] = (double)xr[i * 64 + lane];
    double s = 0.0;
    #pragma unroll
    for (int i = 0; i < 16; ++i) s += xs[i];
    #pragma unroll
    for (int o = 32; o > 0; o >>= 1) s += __shfl_xor(s, o, 64);
    double mean = s * (1.0 / HD);
    double ss = 0.0;
    #pragma unroll
    for (int i = 0; i < 16; ++i) { double d = xs[i] - mean; ss += d * d; }
    #pragma unroll
    for (int o = 32; o > 0; o >>= 1) ss += __shfl_xor(ss, o, 64);
    double inv = 1.0 / sqrt(ss * (1.0 / HD) + 1e-5);

    double ac[NE];
    #pragma unroll
    for (int e = 0; e < NE; ++e) ac[e] = 0.0;
    #pragma unroll
    for (int i = 0; i < 16; ++i) {
        int h = i * 64 + lane;
        double ln = (xs[i] - mean) * inv * (double)gn_g[h] + (double)gn_b[h];
        #pragma unroll
        for (int e = 0; e < NE; ++e) ac[e] += ln * (double)gate_w[h * NE + e];
    }
    #pragma unroll
    for (int e = 0; e < NE; ++e) {
        #pragma unroll
        for (int o = 32; o > 0; o >>= 1) ac[e] += __shfl_xor(ac[e], o, 64);
    }
    if (lane == 0) {
        double lg[NE], p[NE];
        double mx = -1e300;
        #pragma unroll
        for (int e = 0; e < NE; ++e) { lg[e] = ac[e] + (double)gate_b[e]; mx = lg[e] > mx ? lg[e] : mx; }
        double ps = 0.0;
        #pragma unroll
        for (int e = 0; e < NE; ++e) { p[e] = exp(lg[e] - mx); ps += p[e]; }
        #pragma unroll
        for (int e = 0; e < NE; ++e) p[e] /= ps;
        int i0 = 0;
        for (int e = 1; e < NE; ++e) if (p[e] > p[i0]) i0 = e;   // strict > keeps first (jax tie rule)
        int i1 = (i0 == 0) ? 1 : 0;
        for (int e = 0; e < NE; ++e) if (e != i0 && p[e] > p[i1]) i1 = e;
        double den = p[i0] + p[i1] + 1e-9;
        topk_i[t * 2] = i0; topk_i[t * 2 + 1] = i1;
        topk_w[t * 2] = (float)(p[i0] / den);
        topk_w[t * 2 + 1] = (float)(p[i1] / den);
        atomicAdd(&counts[i0], 1);
        atomicAdd(&counts[i1], 1);
    }
}

// ---------------- tiny prefix sum
__global__ void offsets_kernel(const int* __restrict__ counts, int* __restrict__ offs)
{
    if (threadIdx.x == 0) {
        int s = 0;
        for (int e = 0; e < NE; ++e) { offs[e] = s; s += counts[e]; }
        offs[NE] = s;
    }
}

// ---------------- scatter pair ids into expert-grouped list (+ inverse map)
__global__ __launch_bounds__(256) void scatter_kernel(
    const int* __restrict__ topk_i, const int* __restrict__ offs,
    int* __restrict__ cursor, int* __restrict__ pair_tok, int* __restrict__ inv_row)
{
    int idx = blockIdx.x * 256 + threadIdx.x;   // pair id = t*2+k
    if (idx < NPAIR) {
        int e = topk_i[idx];
        int pos = atomicAdd(&cursor[e], 1);
        int dst = offs[e] + pos;
        pair_tok[dst] = idx;
        inv_row[idx] = dst;
    }
}

// ---------------- gather x rows (fp32) -> Xg (bf16, grouped order)
__global__ __launch_bounds__(256) void gather_kernel(
    const float* __restrict__ x, const int* __restrict__ pair_tok, short* __restrict__ Xg)
{
    const int r = blockIdx.x;
    const int t = pair_tok[r] >> 1;
    const int tid = threadIdx.x;
    float4 v = *(const float4*)&x[(size_t)t * HD + tid * 4];
    unsigned w0 = (unsigned)f2bf(v.x) | ((unsigned)f2bf(v.y) << 16);
    unsigned w1 = (unsigned)f2bf(v.z) | ((unsigned)f2bf(v.w) << 16);
    *(uint2*)&Xg[(size_t)r * HD + tid * 4] = make_uint2(w0, w1);
}

#define GLOAD(srcp, dstp) __builtin_amdgcn_global_load_lds(                         \
        (const __attribute__((address_space(1))) unsigned*)(srcp),                  \
        (__attribute__((address_space(3))) unsigned*)(dstp), 16, 0, 0)

// ---------------- grouped GEMM, 256x256 tile, BK=64, 2 LDS dbufs (128 KB),
// 2-phase schedule: per K-tile {STAGE next (8 gloads); 24 ds_read + 64 MFMA
// (compiler-scheduled); lgkm0; vmcnt(0) [drain of loads issued a full iter ago
// -> hidden]; barrier}. ONE barrier per K-tile.
// Granule swizzle: LDS row r, 16B-granule g holds global granule g^(r&7)
// (pre-swizzled global source + swizzled ds_read addr; rule #21; verified r6/r7).
// EPI==1: gelu -> bf16 Hbuf ; EPI==2: +bias -> fp32 Op (both grouped rows)
template<int KDIM, int NDIM, int EPI>
__global__ __launch_bounds__(512, 1) void gemm_kernel(
    const short* __restrict__ A, const short* __restrict__ BT,
    const float* __restrict__ bias, void* __restrict__ outp,
    const int* __restrict__ counts, const int* __restrict__ offs)
{
    // bijective XCD swizzle (nwg % 8 == 0 for all our grids)
    const int nwg = gridDim.x * gridDim.y;
    const int orig = blockIdx.y * gridDim.x + blockIdx.x;
    const int v = (orig & 7) * (nwg >> 3) + (orig >> 3);
    const int bx = v % gridDim.x;             // col tile
    const int by = v / gridDim.x;             // (expert, slot)

    const int tid = threadIdx.x;
    const int e = by >> 3;                    // NSLOT == 8
    const int slot = by & 7;
    const int cnt = counts[e];
    const int colbase = bx * BN;

    __shared__ __align__(16) short As[2 * BM * BK];   // 2 x 32 KB
    __shared__ __align__(16) short Bs[2 * BN * BK];   // 2 x 32 KB

    const int lane = tid & 63;
    const int wv = tid >> 6;                  // 8 waves: 2 M-groups x 4 N-groups
    const int wr = (wv >> 2) * 128, wc = (wv & 3) * 64;
    const int l15 = lane & 15, l4 = lane >> 4;

    // ds_read offsets (shorts): row r, logical granule (l4 + 4*ks); ks=1 = off^32
    const int swb = (l4 ^ (l15 & 7)) * 8;
    int aoff[8], boff[4];
    #pragma unroll
    for (int m = 0; m < 8; ++m)
        aoff[m] = (wr + m * 16 + l15) * BK + swb;
    #pragma unroll
    for (int n = 0; n < 4; ++n)
        boff[n] = (wc + n * 16 + l15) * BK + swb;

    // staging: thread t covers row (64s + t>>3), granule t&7; 4 A + 4 B regions
    const int srow = tid >> 3;                // 0..63
    const int skoff = ((tid & 7) ^ (srow & 7)) << 3;   // pre-swizzled k (shorts)
    const int ldsoff = tid * 8;

    const size_t bbase = (size_t)e * NDIM + colbase;

#define STAGE(db, kb) do {                                                           \
        _Pragma("unroll")                                                            \
        for (int s = 0; s < 4; ++s)                                                  \
            GLOAD(A + (size_t)(rowbase + s * 64 + srow) * KDIM + (kb) + skoff,       \
                  &As[(db) * (BM * BK) + s * 4096 + ldsoff]);                        \
        _Pragma("unroll")                                                            \
        for (int q = 0; q < 4; ++q)                                                  \
            GLOAD(BT + (bbase + q * 64 + srow) * KDIM + (kb) + skoff,                \
                  &Bs[(db) * (BN * BK) + q * 4096 + ldsoff]);                        \
    } while (0)

    constexpr int NKT = KDIM / BK;

    for (int rt = slot; rt * BM < cnt; rt += NSLOT) {
        const int rowbase = offs[e] + rt * BM;

        __syncthreads();   // all buf reads of previous rt complete before restaging
        STAGE(0, 0);
        asm volatile("s_waitcnt vmcnt(0)" ::: "memory");
        __builtin_amdgcn_s_barrier();
        __builtin_amdgcn_sched_barrier(0);

        f32x4 acc[8][4];
        #pragma unroll
        for (int m = 0; m < 8; ++m)
            #pragma unroll
            for (int n = 0; n < 4; ++n)
                acc[m][n] = (f32x4){0.f, 0.f, 0.f, 0.f};

        for (int kt = 0; kt < NKT; ++kt) {
            if (kt + 1 < NKT) STAGE((kt + 1) & 1, (kt + 1) * BK);

            const short* asl = &As[(kt & 1) * (BM * BK)];
            const short* bsl = &Bs[(kt & 1) * (BN * BK)];
            bf16x8 a0[8], a1[8], b0[4], b1[4];
            #pragma unroll
            for (int m = 0; m < 8; ++m) {
                a0[m] = *(const bf16x8*)&asl[aoff[m]];
                a1[m] = *(const bf16x8*)&asl[aoff[m] ^ 32];
            }
            #pragma unroll
            for (int n = 0; n < 4; ++n) {
                b0[n] = *(const bf16x8*)&bsl[boff[n]];
                b1[n] = *(const bf16x8*)&bsl[boff[n] ^ 32];
            }

            __builtin_amdgcn_s_setprio(1);
            #pragma unroll
            for (int m = 0; m < 8; ++m)
                #pragma unroll
                for (int n = 0; n < 4; ++n)
                    acc[m][n] = __builtin_amdgcn_mfma_f32_16x16x32_bf16(a0[m], b0[n], acc[m][n], 0, 0, 0);
            #pragma unroll
            for (int m = 0; m < 8; ++m)
                #pragma unroll
                for (int n = 0; n < 4; ++n)
                    acc[m][n] = __builtin_amdgcn_mfma_f32_16x16x32_bf16(a1[m], b1[n], acc[m][n], 0, 0, 0);
            __builtin_amdgcn_s_setprio(0);

            if (kt < NKT - 1) {
                // own ds_reads done (so next iter's STAGE can't race the reads),
                // and next buffer's gloads (issued at this iter's start) drained.
                asm volatile("s_waitcnt lgkmcnt(0)" ::: "memory");
                __builtin_amdgcn_sched_barrier(0);
                asm volatile("s_waitcnt vmcnt(0)" ::: "memory");
                __builtin_amdgcn_s_barrier();
                __builtin_amdgcn_sched_barrier(0);
            }
        }

        const int rmax = cnt - rt * BM;   // valid rows in this tile (tail tiles < BM)

        if (EPI == 1) {
            short* Hb = (short*)outp;
            #pragma unroll
            for (int n = 0; n < 4; ++n) {
                int col = colbase + wc + n * 16 + l15;
                float bv = bias[e * NDIM + col];
                #pragma unroll
                for (int m = 0; m < 8; ++m) {
                    int r0l = wr + m * 16 + l4 * 4;
                    #pragma unroll
                    for (int r = 0; r < 4; ++r) {
                        int rl = r0l + r;
                        if (rl < rmax) {   // guard: do NOT clobber next expert's rows
                            float vv = acc[m][n][r] + bv;
                            vv = 0.5f * vv * (1.0f + erff(vv * 0.70710678118654752f));
                            Hb[(size_t)(rowbase + rl) * NDIM + col] = (short)f2bf(vv);
                        }
                    }
                }
            }
        } else {
            float* Op = (float*)outp;      // grouped-row order (coalesced tiles)
            #pragma unroll
            for (int n = 0; n < 4; ++n) {
                int col = colbase + wc + n * 16 + l15;
                float bv = bias[e * NDIM + col];
                #pragma unroll
                for (int m = 0; m < 8; ++m) {
                    int r0l = wr + m * 16 + l4 * 4;
                    #pragma unroll
                    for (int r = 0; r < 4; ++r) {
                        int rl = r0l + r;
                        if (rl < rmax)
                            Op[(size_t)(rowbase + rl) * NDIM + col] = acc[m][n][r] + bv;
                    }
                }
            }
        }
    }
#undef STAGE
}

// ---------------- residual + LN + weighted top-k combine (Op in grouped order)
__device__ inline float block_sum256(float v, volatile float* red, int tid)
{
    #pragma unroll
    for (int o = 32; o > 0; o >>= 1) v += __shfl_xor(v, o, 64);
    __syncthreads();
    if ((tid & 63) == 0) red[tid >> 6] = v;
    __syncthreads();
    return red[0] + red[1] + red[2] + red[3];
}

__global__ __launch_bounds__(256) void ln_combine_kernel(
    const float* __restrict__ Op, const float* __restrict__ x,
    const int* __restrict__ topk_i, const float* __restrict__ topk_w,
    const int* __restrict__ inv_row,
    const float* __restrict__ ln_g, const float* __restrict__ ln_b,
    float* __restrict__ y)
{
    __shared__ float red[4];
    const int t = blockIdx.x, tid = threadIdx.x;
    const float4 xr = *(const float4*)&x[(size_t)t * HD + tid * 4];
    float a0 = 0.f, a1 = 0.f, a2 = 0.f, a3 = 0.f;
    #pragma unroll
    for (int k = 0; k < TOPK; ++k) {
        int e = topk_i[t * 2 + k];
        float w = topk_w[t * 2 + k];
        int grow = inv_row[t * 2 + k];
        const float4 o = *(const float4*)&Op[(size_t)grow * HD + tid * 4];
        float v0 = o.x + xr.x, v1 = o.y + xr.y, v2 = o.z + xr.z, v3 = o.w + xr.w;
        float s = block_sum256(v0 + v1 + v2 + v3, red, tid);
        float m = s * (1.0f / HD);
        float d0 = v0 - m, d1 = v1 - m, d2 = v2 - m, d3 = v3 - m;
        float ssq = block_sum256(d0 * d0 + d1 * d1 + d2 * d2 + d3 * d3, red, tid);
        float inv = 1.0f / sqrtf(ssq * (1.0f / HD) + 1e-5f);
        int base = e * HD + tid * 4;
        const float4 g = *(const float4*)&ln_g[base];
        const float4 bb = *(const float4*)&ln_b[base];
        a0 += w * (d0 * inv * g.x + bb.x);
        a1 += w * (d1 * inv * g.y + bb.y);
        a2 += w * (d2 * inv * g.z + bb.z);
        a3 += w * (d3 * inv * g.w + bb.w);
    }
    *(float4*)&y[(size_t)t * HD + tid * 4] = make_float4(a0, a1, a2, a3);
}

__global__ void zero_out_kernel(float* __restrict__ y, int n)
{
    int i = blockIdx.x * 256 + threadIdx.x;
    if (i < n) y[i] = 0.f;
}

extern "C" void kernel_launch(void* const* d_in, const int* in_sizes, int n_in,
                              void* d_out, int out_size, void* d_ws, size_t ws_size,
                              hipStream_t stream)
{
    const float* x      = (const float*)d_in[0];
    const float* W1     = (const float*)d_in[1];
    const float* b1     = (const float*)d_in[2];
    const float* W2     = (const float*)d_in[3];
    const float* b2     = (const float*)d_in[4];
    const float* ln_g   = (const float*)d_in[5];
    const float* ln_b   = (const float*)d_in[6];
    const float* gn_g   = (const float*)d_in[7];
    const float* gn_b   = (const float*)d_in[8];
    const float* gate_w = (const float*)d_in[9];
    const float* gate_b = (const float*)d_in[10];
    float* y = (float*)d_out;

    char* ws = (char*)d_ws;
    size_t off = 0;
    auto take = [&](size_t b) -> char* {
        char* p = ws + off;
        off = (off + b + 255) & ~(size_t)255;
        return p;
    };
    short* W1T     = (short*)take((size_t)NE * FD * HD * 2);       // [E][F][H] bf16
    short* W2T     = (short*)take((size_t)NE * HD * FD * 2);       // [E][H][F] bf16
    short* Xg      = (short*)take((size_t)(NPAIR + PADR) * HD * 2);
    short* Hb      = (short*)take((size_t)(NPAIR + PADR) * FD * 2);
    float* Op      = (float*)take((size_t)NPAIR * HD * 4);         // grouped rows
    int*   topk_i  = (int*)take(NPAIR * 4);
    float* topk_w  = (float*)take(NPAIR * 4);
    int*   cnts    = (int*)take(64);            // 8 counts + 8 cursor
    int*   cursor  = cnts + 8;
    int*   offs    = (int*)take(64);
    int*   pair_tok= (int*)take((size_t)(NPAIR + PADR) * 4);
    int*   inv_row = (int*)take((size_t)NPAIR * 4);

    if (ws_size < off) {   // workspace too small: emit zeros so failure mode is diagnosable
        zero_out_kernel<<<(out_size + 255) / 256, 256, 0, stream>>>(y, out_size);
        return;
    }

    hipMemsetAsync(cnts, 0, 64, stream);

    transpose_cvt_kernel<HD, FD><<<dim3(FD / 64, HD / 64, NE), 256, 0, stream>>>(W1, W1T);
    transpose_cvt_kernel<FD, HD><<<dim3(HD / 64, FD / 64, NE), 256, 0, stream>>>(W2, W2T);

    gating_kernel<<<TOK / 4, 256, 0, stream>>>(x, gn_g, gn_b, gate_w, gate_b, topk_i, topk_w, cnts);
    offsets_kernel<<<1, 64, 0, stream>>>(cnts, offs);
    scatter_kernel<<<NPAIR / 256, 256, 0, stream>>>(topk_i, offs, cursor, pair_tok, inv_row);
    gather_kernel<<<NPAIR, 256, 0, stream>>>(x, pair_tok, Xg);

    // GEMM1: [pairs x HD] @ W1T -> gelu -> Hb   (16 col tiles x 64 (e,slot))
    gemm_kernel<HD, FD, 1><<<dim3(FD / BN, NE * NSLOT), 512, 0, stream>>>(
        Xg, W1T, b1, (void*)Hb, cnts, offs);
    // GEMM2: [pairs x FD] @ W2T -> +b2 -> Op (grouped)   (4 col tiles x 64)
    gemm_kernel<FD, HD, 2><<<dim3(HD / BN, NE * NSLOT), 512, 0, stream>>>(
        Hb, W2T, b2, (void*)Op, cnts, offs);

    ln_combine_kernel<<<TOK, 256, 0, stream>>>(Op, x, topk_i, topk_w, inv_row, ln_g, ln_b, y);
}

// Round 10
// 1007.849 us; speedup vs baseline: 1.0578x; 1.0403x over previous
//
#include <hip/hip_runtime.h>
#include <hip/hip_bf16.h>

#define TOK   8192      // B*S
#define HD    1024      // H
#define FD    4096      // F
#define NE    8         // E
#define TOPK  2
#define NPAIR (TOK*TOPK)   // 16384, fixed
#define PADR  256          // row padding for tile overrun
#define NSLOT 8            // row-tile slots per expert
#define BM    256
#define BN    256

typedef short bf16x8 __attribute__((ext_vector_type(8)));
typedef float f32x4  __attribute__((ext_vector_type(4)));

__device__ inline unsigned short f2bf(float f) {
    unsigned u = __float_as_uint(f);
    unsigned r = (u + 0x7fffu + ((u >> 16) & 1u)) >> 16;
    return (unsigned short)r;
}

// ---------------- transpose + fp32->bf16 convert: in [E][R][C] -> out [E][C][R]
template<int R, int C>
__global__ __launch_bounds__(256) void transpose_cvt_kernel(
    const float* __restrict__ in, short* __restrict__ out)
{
    __shared__ float tile[64][65];
    const int tid = threadIdx.x;
    const int c0 = blockIdx.x * 64, r0 = blockIdx.y * 64, e = blockIdx.z;
    #pragma unroll
    for (int i = 0; i < 4; ++i) {
        int idx = i * 1024 + tid * 4;
        int rr = idx >> 6, cc = idx & 63;
        float4 v = *(const float4*)&in[((size_t)e * R + r0 + rr) * C + c0 + cc];
        tile[rr][cc] = v.x; tile[rr][cc + 1] = v.y;
        tile[rr][cc + 2] = v.z; tile[rr][cc + 3] = v.w;
    }
    __syncthreads();
    #pragma unroll
    for (int i = 0; i < 8; ++i) {
        int idx = i * 256 + tid;
        int cc = idx >> 5, rp = idx & 31;
        unsigned lo = f2bf(tile[rp * 2][cc]);
        unsigned hi = f2bf(tile[rp * 2 + 1][cc]);
        unsigned w = lo | (hi << 16);
        *(unsigned*)&out[((size_t)e * C + c0 + cc) * R + r0 + rp * 2] = w;
    }
}

// ---------------- gating: fp64 LN + logits + softmax + top-2 (one wave per token)
__global__ __launch_bounds__(256) void gating_kernel(
    const float* __restrict__ x, const float* __restrict__ gn_g, const float* __restrict__ gn_b,
    const float* __restrict__ gate_w, const float* __restrict__ gate_b,
    int* __restrict__ topk_i, float* __restrict__ topk_w, int* __restrict__ counts)
{
    const int wv = threadIdx.x >> 6, lane = threadIdx.x & 63;
    const int t = blockIdx.x * 4 + wv;
    const float* xr = x + (size_t)t * HD;

    double xs[16];
    #pragma unroll
    for (int i = 0; i < 16; ++i) xs[i] = (double)xr[i * 64 + lane];
    double s = 0.0;
    #pragma unroll
    for (int i = 0; i < 16; ++i) s += xs[i];
    #pragma unroll
    for (int o = 32; o > 0; o >>= 1) s += __shfl_xor(s, o, 64);
    double mean = s * (1.0 / HD);
    double ss = 0.0;
    #pragma unroll
    for (int i = 0; i < 16; ++i) { double d = xs[i] - mean; ss += d * d; }
    #pragma unroll
    for (int o = 32; o > 0; o >>= 1) ss += __shfl_xor(ss, o, 64);
    double inv = 1.0 / sqrt(ss * (1.0 / HD) + 1e-5);

    double ac[NE];
    #pragma unroll
    for (int e = 0; e < NE; ++e) ac[e] = 0.0;
    #pragma unroll
    for (int i = 0; i < 16; ++i) {
        int h = i * 64 + lane;
        double ln = (xs[i] - mean) * inv * (double)gn_g[h] + (double)gn_b[h];
        #pragma unroll
        for (int e = 0; e < NE; ++e) ac[e] += ln * (double)gate_w[h * NE + e];
    }
    #pragma unroll
    for (int e = 0; e < NE; ++e) {
        #pragma unroll
        for (int o = 32; o > 0; o >>= 1) ac[e] += __shfl_xor(ac[e], o, 64);
    }
    if (lane == 0) {
        double lg[NE], p[NE];
        double mx = -1e300;
        #pragma unroll
        for (int e = 0; e < NE; ++e) { lg[e] = ac[e] + (double)gate_b[e]; mx = lg[e] > mx ? lg[e] : mx; }
        double ps = 0.0;
        #pragma unroll
        for (int e = 0; e < NE; ++e) { p[e] = exp(lg[e] - mx); ps += p[e]; }
        #pragma unroll
        for (int e = 0; e < NE; ++e) p[e] /= ps;
        int i0 = 0;
        for (int e = 1; e < NE; ++e) if (p[e] > p[i0]) i0 = e;   // strict > keeps first (jax tie rule)
        int i1 = (i0 == 0) ? 1 : 0;
        for (int e = 0; e < NE; ++e) if (e != i0 && p[e] > p[i1]) i1 = e;
        double den = p[i0] + p[i1] + 1e-9;
        topk_i[t * 2] = i0; topk_i[t * 2 + 1] = i1;
        topk_w[t * 2] = (float)(p[i0] / den);
        topk_w[t * 2 + 1] = (float)(p[i1] / den);
        atomicAdd(&counts[i0], 1);
        atomicAdd(&counts[i1], 1);
    }
}

// ---------------- tiny prefix sum
__global__ void offsets_kernel(const int* __restrict__ counts, int* __restrict__ offs)
{
    if (threadIdx.x == 0) {
        int s = 0;
        for (int e = 0; e < NE; ++e) { offs[e] = s; s += counts[e]; }
        offs[NE] = s;
    }
}

// ---------------- scatter pair ids into expert-grouped list (+ inverse map)
__global__ __launch_bounds__(256) void scatter_kernel(
    const int* __restrict__ topk_i, const int* __restrict__ offs,
    int* __restrict__ cursor, int* __restrict__ pair_tok, int* __restrict__ inv_row)
{
    int idx = blockIdx.x * 256 + threadIdx.x;   // pair id = t*2+k
    if (idx < NPAIR) {
        int e = topk_i[idx];
        int pos = atomicAdd(&cursor[e], 1);
        int dst = offs[e] + pos;
        pair_tok[dst] = idx;
        inv_row[idx] = dst;
    }
}

// ---------------- gather x rows (fp32) -> Xg (bf16, grouped order)
__global__ __launch_bounds__(256) void gather_kernel(
    const float* __restrict__ x, const int* __restrict__ pair_tok, short* __restrict__ Xg)
{
    const int r = blockIdx.x;
    const int t = pair_tok[r] >> 1;
    const int tid = threadIdx.x;
    float4 v = *(const float4*)&x[(size_t)t * HD + tid * 4];
    unsigned w0 = (unsigned)f2bf(v.x) | ((unsigned)f2bf(v.y) << 16);
    unsigned w1 = (unsigned)f2bf(v.z) | ((unsigned)f2bf(v.w) << 16);
    *(uint2*)&Xg[(size_t)r * HD + tid * 4] = make_uint2(w0, w1);
}

#define GLOAD(srcp, dstp) __builtin_amdgcn_global_load_lds(                         \
        (const __attribute__((address_space(1))) unsigned*)(srcp),                  \
        (__attribute__((address_space(3))) unsigned*)(dstp), 16, 0, 0)

#define OPENV(n) do { asm volatile("s_waitcnt vmcnt(" #n ")" ::: "memory");         \
                      __builtin_amdgcn_s_barrier();                                 \
                      __builtin_amdgcn_sched_barrier(0); } while (0)
#define OPENB    do { __builtin_amdgcn_s_barrier();                                 \
                      __builtin_amdgcn_sched_barrier(0); } while (0)

// ---------------- grouped GEMM, 256x256 tile, BK=64, 8-phase-style schedule.
// 2 dbufs x (4 A-quarters + 4 B-quarters) of 64rows x 64k (8KB each) = 128 KB LDS.
// 4 phases per K-tile, 16 MFMA each; per phase: {ds_read 4-8 frag; stage 2 quarter
// regions for kt+1 into other dbuf; setprio MFMA}. Counted waits: vmcnt(2) at
// phases 1-2, bare barrier phases 3-4, vmcnt(0) only at last K-tile phase 2.
// Granule swizzle (verified r6/r7): phys granule g of row r holds global granule
// g^(r&7); applied pre-swizzled on global source AND on ds_read addr (rule #21).
// EPI==1: gelu -> bf16 Hbuf ; EPI==2: +bias -> fp32 Op (both grouped rows)
template<int KDIM, int NDIM, int EPI>
__global__ __launch_bounds__(512, 2) void gemm_kernel(
    const short* __restrict__ A, const short* __restrict__ BT,
    const float* __restrict__ bias, void* __restrict__ outp,
    const int* __restrict__ counts, const int* __restrict__ offs)
{
    // bijective XCD swizzle (nwg % 8 == 0 for all our grids)
    const int nwg = gridDim.x * gridDim.y;
    const int orig = blockIdx.y * gridDim.x + blockIdx.x;
    const int v = (orig & 7) * (nwg >> 3) + (orig >> 3);
    const int bx = v % gridDim.x;             // col tile
    const int by = v / gridDim.x;             // (expert, slot)

    const int tid = threadIdx.x;
    const int e = by >> 3;                    // NSLOT == 8
    const int slot = by & 7;
    const int cnt = counts[e];
    const int colbase = bx * BN;

    __shared__ __align__(16) short As[2 * 16384];   // [db][q][64r][64k] -> 64 KB
    __shared__ __align__(16) short Bs[2 * 16384];   // 64 KB

    const int lane = tid & 63;
    const int wv = tid >> 6;                  // 8 waves: 2 M-groups x 4 N-groups
    const int wr = (wv >> 2) * 128, wc = (wv & 3) * 64;
    const int l15 = lane & 15, l4 = lane >> 4;

    // ds_read offsets (shorts): ks0; ks1 = off ^ 32 (phys granule ^4)
    int aoff[8], boff[4];
    #pragma unroll
    for (int m = 0; m < 8; ++m) {
        int R = wr + m * 16 + l15;
        int q = R >> 6, r = R & 63;
        aoff[m] = q * 4096 + r * 64 + ((l4 ^ (r & 7)) << 3);
    }
    #pragma unroll
    for (int n = 0; n < 4; ++n) {
        int r = n * 16 + l15;
        boff[n] = (wv & 3) * 4096 + r * 64 + ((l4 ^ (r & 7)) << 3);
    }

    // staging: thread covers (row=tid>>3, granule=tid&7) of one 64x64 quarter
    const int srow = tid >> 3;
    const int skoff = ((tid & 7) ^ (srow & 7)) << 3;   // pre-swizzled k (shorts)
    const int dlds = tid * 8;

    const size_t bbase = (size_t)e * NDIM + colbase;

#define SQA(db, q, kb) GLOAD(A + (size_t)(rowbase + (q) * 64 + srow) * KDIM + (kb) + skoff, \
                             &As[(db) * 16384 + (q) * 4096 + dlds])
#define SQB(db, q, kb) GLOAD(BT + (bbase + (q) * 64 + srow) * KDIM + (kb) + skoff,          \
                             &Bs[(db) * 16384 + (q) * 4096 + dlds])

    constexpr int NKT = KDIM / 64;

    for (int rt = slot; rt * BM < cnt; rt += NSLOT) {
        const int rowbase = offs[e] + rt * BM;

        __syncthreads();   // prior rt readers done before restaging dbuf0

        // prologue: K-tile 0 -> dbuf0; newest 2 stages = Aq1,Aq3 (not needed at ph1)
        SQB(0, 0, 0); SQB(0, 1, 0); SQB(0, 2, 0); SQB(0, 3, 0);
        SQA(0, 0, 0); SQA(0, 2, 0); SQA(0, 1, 0); SQA(0, 3, 0);

        f32x4 acc[8][4];
        #pragma unroll
        for (int m = 0; m < 8; ++m)
            #pragma unroll
            for (int n = 0; n < 4; ++n)
                acc[m][n] = (f32x4){0.f, 0.f, 0.f, 0.f};

        for (int kt = 0; kt < NKT; ++kt) {
            const int cb = (kt & 1) * 16384;
            const int nb = (kt + 1) & 1;
            const int kb1 = (kt + 1) * 64;
            const bool do1 = (kt + 1 < NKT);
            const short* asl = &As[cb];
            const short* bsl = &Bs[cb];
            bf16x8 af[4], bf[4];

            // ---- phase 1: ks0, m0-3 (+ B ks0 reads); stage Bq0,Bq1 for kt+1
            OPENV(2);
            #pragma unroll
            for (int m = 0; m < 4; ++m) af[m] = *(const bf16x8*)&asl[aoff[m]];
            #pragma unroll
            for (int n = 0; n < 4; ++n) bf[n] = *(const bf16x8*)&bsl[boff[n]];
            if (do1) { SQB(nb, 0, kb1); SQB(nb, 1, kb1); }
            __builtin_amdgcn_s_setprio(1);
            #pragma unroll
            for (int m = 0; m < 4; ++m)
                #pragma unroll
                for (int n = 0; n < 4; ++n)
                    acc[m][n] = __builtin_amdgcn_mfma_f32_16x16x32_bf16(af[m], bf[n], acc[m][n], 0, 0, 0);
            __builtin_amdgcn_s_setprio(0);

            // ---- phase 2: ks0, m4-7 (reuse bf); stage Bq2,Bq3
            if (do1) { OPENV(2); } else { OPENV(0); }
            #pragma unroll
            for (int m = 0; m < 4; ++m) af[m] = *(const bf16x8*)&asl[aoff[4 + m]];
            if (do1) { SQB(nb, 2, kb1); SQB(nb, 3, kb1); }
            __builtin_amdgcn_s_setprio(1);
            #pragma unroll
            for (int m = 0; m < 4; ++m)
                #pragma unroll
                for (int n = 0; n < 4; ++n)
                    acc[4 + m][n] = __builtin_amdgcn_mfma_f32_16x16x32_bf16(af[m], bf[n], acc[4 + m][n], 0, 0, 0);
            __builtin_amdgcn_s_setprio(0);

            // ---- phase 3: ks1, m0-3 (+ B ks1 reads); stage Aq0,Aq2
            OPENB;
            #pragma unroll
            for (int m = 0; m < 4; ++m) af[m] = *(const bf16x8*)&asl[aoff[m] ^ 32];
            #pragma unroll
            for (int n = 0; n < 4; ++n) bf[n] = *(const bf16x8*)&bsl[boff[n] ^ 32];
            if (do1) { SQA(nb, 0, kb1); SQA(nb, 2, kb1); }
            __builtin_amdgcn_s_setprio(1);
            #pragma unroll
            for (int m = 0; m < 4; ++m)
                #pragma unroll
                for (int n = 0; n < 4; ++n)
                    acc[m][n] = __builtin_amdgcn_mfma_f32_16x16x32_bf16(af[m], bf[n], acc[m][n], 0, 0, 0);
            __builtin_amdgcn_s_setprio(0);

            // ---- phase 4: ks1, m4-7 (reuse bf); stage Aq1,Aq3
            OPENB;
            #pragma unroll
            for (int m = 0; m < 4; ++m) af[m] = *(const bf16x8*)&asl[aoff[4 + m] ^ 32];
            if (do1) { SQA(nb, 1, kb1); SQA(nb, 3, kb1); }
            __builtin_amdgcn_s_setprio(1);
            #pragma unroll
            for (int m = 0; m < 4; ++m)
                #pragma unroll
                for (int n = 0; n < 4; ++n)
                    acc[4 + m][n] = __builtin_amdgcn_mfma_f32_16x16x32_bf16(af[m], bf[n], acc[4 + m][n], 0, 0, 0);
            __builtin_amdgcn_s_setprio(0);
        }

        const int rmax = cnt - rt * BM;   // valid rows in this tile (tail tiles < BM)

        if (EPI == 1) {
            short* Hb = (short*)outp;
            #pragma unroll
            for (int n = 0; n < 4; ++n) {
                int col = colbase + wc + n * 16 + l15;
                float bv = bias[e * NDIM + col];
                #pragma unroll
                for (int m = 0; m < 8; ++m) {
                    int r0l = wr + m * 16 + l4 * 4;
                    #pragma unroll
                    for (int r = 0; r < 4; ++r) {
                        int rl = r0l + r;
                        if (rl < rmax) {   // guard: do NOT clobber next expert's rows
                            float vv = acc[m][n][r] + bv;
                            vv = 0.5f * vv * (1.0f + erff(vv * 0.70710678118654752f));
                            Hb[(size_t)(rowbase + rl) * NDIM + col] = (short)f2bf(vv);
                        }
                    }
                }
            }
        } else {
            float* Op = (float*)outp;      // grouped-row order (coalesced tiles)
            #pragma unroll
            for (int n = 0; n < 4; ++n) {
                int col = colbase + wc + n * 16 + l15;
                float bv = bias[e * NDIM + col];
                #pragma unroll
                for (int m = 0; m < 8; ++m) {
                    int r0l = wr + m * 16 + l4 * 4;
                    #pragma unroll
                    for (int r = 0; r < 4; ++r) {
                        int rl = r0l + r;
                        if (rl < rmax)
                            Op[(size_t)(rowbase + rl) * NDIM + col] = acc[m][n][r] + bv;
                    }
                }
            }
        }
    }
#undef SQA
#undef SQB
}

// ---------------- residual + LN + weighted top-k combine (Op in grouped order)
__device__ inline float block_sum256(float v, volatile float* red, int tid)
{
    #pragma unroll
    for (int o = 32; o > 0; o >>= 1) v += __shfl_xor(v, o, 64);
    __syncthreads();
    if ((tid & 63) == 0) red[tid >> 6] = v;
    __syncthreads();
    return red[0] + red[1] + red[2] + red[3];
}

__global__ __launch_bounds__(256) void ln_combine_kernel(
    const float* __restrict__ Op, const float* __restrict__ x,
    const int* __restrict__ topk_i, const float* __restrict__ topk_w,
    const int* __restrict__ inv_row,
    const float* __restrict__ ln_g, const float* __restrict__ ln_b,
    float* __restrict__ y)
{
    __shared__ float red[4];
    const int t = blockIdx.x, tid = threadIdx.x;
    const float4 xr = *(const float4*)&x[(size_t)t * HD + tid * 4];
    float a0 = 0.f, a1 = 0.f, a2 = 0.f, a3 = 0.f;
    #pragma unroll
    for (int k = 0; k < TOPK; ++k) {
        int e = topk_i[t * 2 + k];
        float w = topk_w[t * 2 + k];
        int grow = inv_row[t * 2 + k];
        const float4 o = *(const float4*)&Op[(size_t)grow * HD + tid * 4];
        float v0 = o.x + xr.x, v1 = o.y + xr.y, v2 = o.z + xr.z, v3 = o.w + xr.w;
        float s = block_sum256(v0 + v1 + v2 + v3, red, tid);
        float m = s * (1.0f / HD);
        float d0 = v0 - m, d1 = v1 - m, d2 = v2 - m, d3 = v3 - m;
        float ssq = block_sum256(d0 * d0 + d1 * d1 + d2 * d2 + d3 * d3, red, tid);
        float inv = 1.0f / sqrtf(ssq * (1.0f / HD) + 1e-5f);
        int base = e * HD + tid * 4;
        const float4 g = *(const float4*)&ln_g[base];
        const float4 bb = *(const float4*)&ln_b[base];
        a0 += w * (d0 * inv * g.x + bb.x);
        a1 += w * (d1 * inv * g.y + bb.y);
        a2 += w * (d2 * inv * g.z + bb.z);
        a3 += w * (d3 * inv * g.w + bb.w);
    }
    *(float4*)&y[(size_t)t * HD + tid * 4] = make_float4(a0, a1, a2, a3);
}

__global__ void zero_out_kernel(float* __restrict__ y, int n)
{
    int i = blockIdx.x * 256 + threadIdx.x;
    if (i < n) y[i] = 0.f;
}

extern "C" void kernel_launch(void* const* d_in, const int* in_sizes, int n_in,
                              void* d_out, int out_size, void* d_ws, size_t ws_size,
                              hipStream_t stream)
{
    const float* x      = (const float*)d_in[0];
    const float* W1     = (const float*)d_in[1];
    const float* b1     = (const float*)d_in[2];
    const float* W2     = (const float*)d_in[3];
    const float* b2     = (const float*)d_in[4];
    const float* ln_g   = (const float*)d_in[5];
    const float* ln_b   = (const float*)d_in[6];
    const float* gn_g   = (const float*)d_in[7];
    const float* gn_b   = (const float*)d_in[8];
    const float* gate_w = (const float*)d_in[9];
    const float* gate_b = (const float*)d_in[10];
    float* y = (float*)d_out;

    char* ws = (char*)d_ws;
    size_t off = 0;
    auto take = [&](size_t b) -> char* {
        char* p = ws + off;
        off = (off + b + 255) & ~(size_t)255;
        return p;
    };
    short* W1T     = (short*)take((size_t)NE * FD * HD * 2);       // [E][F][H] bf16
    short* W2T     = (short*)take((size_t)NE * HD * FD * 2);       // [E][H][F] bf16
    short* Xg      = (short*)take((size_t)(NPAIR + PADR) * HD * 2);
    short* Hb      = (short*)take((size_t)(NPAIR + PADR) * FD * 2);
    float* Op      = (float*)take((size_t)NPAIR * HD * 4);         // grouped rows
    int*   topk_i  = (int*)take(NPAIR * 4);
    float* topk_w  = (float*)take(NPAIR * 4);
    int*   cnts    = (int*)take(64);            // 8 counts + 8 cursor
    int*   cursor  = cnts + 8;
    int*   offs    = (int*)take(64);
    int*   pair_tok= (int*)take((size_t)(NPAIR + PADR) * 4);
    int*   inv_row = (int*)take((size_t)NPAIR * 4);

    if (ws_size < off) {   // workspace too small: emit zeros so failure mode is diagnosable
        zero_out_kernel<<<(out_size + 255) / 256, 256, 0, stream>>>(y, out_size);
        return;
    }

    hipMemsetAsync(cnts, 0, 64, stream);

    transpose_cvt_kernel<HD, FD><<<dim3(FD / 64, HD / 64, NE), 256, 0, stream>>>(W1, W1T);
    transpose_cvt_kernel<FD, HD><<<dim3(HD / 64, FD / 64, NE), 256, 0, stream>>>(W2, W2T);

    gating_kernel<<<TOK / 4, 256, 0, stream>>>(x, gn_g, gn_b, gate_w, gate_b, topk_i, topk_w, cnts);
    offsets_kernel<<<1, 64, 0, stream>>>(cnts, offs);
    scatter_kernel<<<NPAIR / 256, 256, 0, stream>>>(topk_i, offs, cursor, pair_tok, inv_row);
    gather_kernel<<<NPAIR, 256, 0, stream>>>(x, pair_tok, Xg);

    // GEMM1: [pairs x HD] @ W1T -> gelu -> Hb   (16 col tiles x 64 (e,slot))
    gemm_kernel<HD, FD, 1><<<dim3(FD / BN, NE * NSLOT), 512, 0, stream>>>(
        Xg, W1T, b1, (void*)Hb, cnts, offs);
    // GEMM2: [pairs x FD] @ W2T -> +b2 -> Op (grouped)   (4 col tiles x 64)
    gemm_kernel<FD, HD, 2><<<dim3(HD / BN, NE * NSLOT), 512, 0, stream>>>(
        Hb, W2T, b2, (void*)Op, cnts, offs);

    ln_combine_kernel<<<TOK, 256, 0, stream>>>(Op, x, topk_i, topk_w, inv_row, ln_g, ln_b, y);
}

// Round 11
// 969.738 us; speedup vs baseline: 1.0994x; 1.0393x over previous
//
#include <hip/hip_runtime.h>
#include <hip/hip_bf16.h>

#define TOK   8192      // B*S
#define HD    1024      // H
#define FD    4096      // F
#define NE    8         // E
#define TOPK  2
#define NPAIR (TOK*TOPK)   // 16384, fixed
#define PADR  256          // row padding for tile overrun
#define NSLOT 8            // row-tile slots per expert
#define BM    256
#define BN    256
#define BK    64

typedef short bf16x8 __attribute__((ext_vector_type(8)));
typedef float f32x4  __attribute__((ext_vector_type(4)));

__device__ inline unsigned short f2bf(float f) {
    unsigned u = __float_as_uint(f);
    unsigned r = (u + 0x7fffu + ((u >> 16) & 1u)) >> 16;
    return (unsigned short)r;
}

// ---------------- transpose + fp32->bf16 convert: in [E][R][C] -> out [E][C][R]
template<int R, int C>
__global__ __launch_bounds__(256) void transpose_cvt_kernel(
    const float* __restrict__ in, short* __restrict__ out)
{
    __shared__ float tile[64][65];
    const int tid = threadIdx.x;
    const int c0 = blockIdx.x * 64, r0 = blockIdx.y * 64, e = blockIdx.z;
    #pragma unroll
    for (int i = 0; i < 4; ++i) {
        int idx = i * 1024 + tid * 4;
        int rr = idx >> 6, cc = idx & 63;
        float4 v = *(const float4*)&in[((size_t)e * R + r0 + rr) * C + c0 + cc];
        tile[rr][cc] = v.x; tile[rr][cc + 1] = v.y;
        tile[rr][cc + 2] = v.z; tile[rr][cc + 3] = v.w;
    }
    __syncthreads();
    #pragma unroll
    for (int i = 0; i < 8; ++i) {
        int idx = i * 256 + tid;
        int cc = idx >> 5, rp = idx & 31;
        unsigned lo = f2bf(tile[rp * 2][cc]);
        unsigned hi = f2bf(tile[rp * 2 + 1][cc]);
        unsigned w = lo | (hi << 16);
        *(unsigned*)&out[((size_t)e * C + c0 + cc) * R + r0 + rp * 2] = w;
    }
}

// ---------------- gating: fp64 LN + logits + softmax + top-2 (one wave per token)
__global__ __launch_bounds__(256) void gating_kernel(
    const float* __restrict__ x, const float* __restrict__ gn_g, const float* __restrict__ gn_b,
    const float* __restrict__ gate_w, const float* __restrict__ gate_b,
    int* __restrict__ topk_i, float* __restrict__ topk_w, int* __restrict__ counts)
{
    const int wv = threadIdx.x >> 6, lane = threadIdx.x & 63;
    const int t = blockIdx.x * 4 + wv;
    const float* xr = x + (size_t)t * HD;

    double xs[16];
    #pragma unroll
    for (int i = 0; i < 16; ++i) xs[i] = (double)xr[i * 64 + lane];
    double s = 0.0;
    #pragma unroll
    for (int i = 0; i < 16; ++i) s += xs[i];
    #pragma unroll
    for (int o = 32; o > 0; o >>= 1) s += __shfl_xor(s, o, 64);
    double mean = s * (1.0 / HD);
    double ss = 0.0;
    #pragma unroll
    for (int i = 0; i < 16; ++i) { double d = xs[i] - mean; ss += d * d; }
    #pragma unroll
    for (int o = 32; o > 0; o >>= 1) ss += __shfl_xor(ss, o, 64);
    double inv = 1.0 / sqrt(ss * (1.0 / HD) + 1e-5);

    double ac[NE];
    #pragma unroll
    for (int e = 0; e < NE; ++e) ac[e] = 0.0;
    #pragma unroll
    for (int i = 0; i < 16; ++i) {
        int h = i * 64 + lane;
        double ln = (xs[i] - mean) * inv * (double)gn_g[h] + (double)gn_b[h];
        #pragma unroll
        for (int e = 0; e < NE; ++e) ac[e] += ln * (double)gate_w[h * NE + e];
    }
    #pragma unroll
    for (int e = 0; e < NE; ++e) {
        #pragma unroll
        for (int o = 32; o > 0; o >>= 1) ac[e] += __shfl_xor(ac[e], o, 64);
    }
    if (lane == 0) {
        double lg[NE], p[NE];
        double mx = -1e300;
        #pragma unroll
        for (int e = 0; e < NE; ++e) { lg[e] = ac[e] + (double)gate_b[e]; mx = lg[e] > mx ? lg[e] : mx; }
        double ps = 0.0;
        #pragma unroll
        for (int e = 0; e < NE; ++e) { p[e] = exp(lg[e] - mx); ps += p[e]; }
        #pragma unroll
        for (int e = 0; e < NE; ++e) p[e] /= ps;
        int i0 = 0;
        for (int e = 1; e < NE; ++e) if (p[e] > p[i0]) i0 = e;   // strict > keeps first (jax tie rule)
        int i1 = (i0 == 0) ? 1 : 0;
        for (int e = 0; e < NE; ++e) if (e != i0 && p[e] > p[i1]) i1 = e;
        double den = p[i0] + p[i1] + 1e-9;
        topk_i[t * 2] = i0; topk_i[t * 2 + 1] = i1;
        topk_w[t * 2] = (float)(p[i0] / den);
        topk_w[t * 2 + 1] = (float)(p[i1] / den);
        atomicAdd(&counts[i0], 1);
        atomicAdd(&counts[i1], 1);
    }
}

// ---------------- tiny prefix sum
__global__ void offsets_kernel(const int* __restrict__ counts, int* __restrict__ offs)
{
    if (threadIdx.x == 0) {
        int s = 0;
        for (int e = 0; e < NE; ++e) { offs[e] = s; s += counts[e]; }
        offs[NE] = s;
    }
}

// ---------------- scatter pair ids into expert-grouped list (+ inverse map)
__global__ __launch_bounds__(256) void scatter_kernel(
    const int* __restrict__ topk_i, const int* __restrict__ offs,
    int* __restrict__ cursor, int* __restrict__ pair_tok, int* __restrict__ inv_row)
{
    int idx = blockIdx.x * 256 + threadIdx.x;   // pair id = t*2+k
    if (idx < NPAIR) {
        int e = topk_i[idx];
        int pos = atomicAdd(&cursor[e], 1);
        int dst = offs[e] + pos;
        pair_tok[dst] = idx;
        inv_row[idx] = dst;
    }
}

// ---------------- gather x rows (fp32) -> Xg (bf16, grouped order)
__global__ __launch_bounds__(256) void gather_kernel(
    const float* __restrict__ x, const int* __restrict__ pair_tok, short* __restrict__ Xg)
{
    const int r = blockIdx.x;
    const int t = pair_tok[r] >> 1;
    const int tid = threadIdx.x;
    float4 v = *(const float4*)&x[(size_t)t * HD + tid * 4];
    unsigned w0 = (unsigned)f2bf(v.x) | ((unsigned)f2bf(v.y) << 16);
    unsigned w1 = (unsigned)f2bf(v.z) | ((unsigned)f2bf(v.w) << 16);
    *(uint2*)&Xg[(size_t)r * HD + tid * 4] = make_uint2(w0, w1);
}

#define GLOAD(srcp, dstp) __builtin_amdgcn_global_load_lds(                         \
        (const __attribute__((address_space(1))) unsigned*)(srcp),                  \
        (__attribute__((address_space(3))) unsigned*)(dstp), 16, 0, 0)

// ---------------- grouped GEMM, 256x256 tile, BK=64, 2 LDS dbufs (128 KB, 1 blk/CU),
// m230-style 2-phase: per K-tile { STAGE next tile (8 gloads); read ks0 frags;
// 32 MFMA; read ks1 frags; 32 MFMA; __syncthreads() }.
// The barrier's implicit vmcnt(0) drains loads issued ~640 MFMA-cycles earlier
// -> latency hidden. Half-K fragment split keeps live VGPRs ~110 (no spill at
// the 128-reg cap from __launch_bounds__(512,2); acc lives in AGPRs).
// Granule swizzle (verified r6/r7 conflict-free): phys 16B-granule g of row r
// holds global granule g^(r&7); applied on pre-swizzled global source AND on
// ds_read addr (rule #21).
// EPI==1: gelu -> bf16 Hbuf ; EPI==2: +bias -> fp32 Op (both grouped rows)
template<int KDIM, int NDIM, int EPI>
__global__ __launch_bounds__(512, 2) void gemm_kernel(
    const short* __restrict__ A, const short* __restrict__ BT,
    const float* __restrict__ bias, void* __restrict__ outp,
    const int* __restrict__ counts, const int* __restrict__ offs)
{
    // bijective XCD swizzle (nwg % 8 == 0 for all our grids)
    const int nwg = gridDim.x * gridDim.y;
    const int orig = blockIdx.y * gridDim.x + blockIdx.x;
    const int v = (orig & 7) * (nwg >> 3) + (orig >> 3);
    const int bx = v % gridDim.x;             // col tile
    const int by = v / gridDim.x;             // (expert, slot)

    const int tid = threadIdx.x;
    const int e = by >> 3;                    // NSLOT == 8
    const int slot = by & 7;
    const int cnt = counts[e];
    const int colbase = bx * BN;

    __shared__ __align__(16) short As[2 * BM * BK];   // 2 x 32 KB
    __shared__ __align__(16) short Bs[2 * BN * BK];   // 2 x 32 KB

    const int lane = tid & 63;
    const int wv = tid >> 6;                  // 8 waves: 2 M-groups x 4 N-groups
    const int wr = (wv >> 2) * 128, wc = (wv & 3) * 64;
    const int l15 = lane & 15, l4 = lane >> 4;

    // ds_read offsets (shorts): row r, ks0 granule l4; ks1 = off ^ 32
    int aoff[8], boff[4];
    #pragma unroll
    for (int m = 0; m < 8; ++m) {
        int r = wr + m * 16 + l15;
        aoff[m] = r * BK + ((l4 ^ (r & 7)) << 3);
    }
    #pragma unroll
    for (int n = 0; n < 4; ++n) {
        int r = wc + n * 16 + l15;
        boff[n] = r * BK + ((l4 ^ (r & 7)) << 3);
    }

    // staging: granule G = tid + 512*s; row = G>>3 (8 granules/row), gran = tid&7
    const int srow = tid >> 3;                // 0..63 (+64 per s)
    const int skoff = ((tid & 7) ^ (srow & 7)) << 3;   // pre-swizzled k (shorts)
    const int dlds = tid * 8;

    const size_t bbase = (size_t)e * NDIM + colbase;

#define STAGE(db, kb) do {                                                           \
        _Pragma("unroll")                                                            \
        for (int s = 0; s < 4; ++s)                                                  \
            GLOAD(A + (size_t)(rowbase + s * 64 + srow) * KDIM + (kb) + skoff,       \
                  &As[(db) * (BM * BK) + s * 4096 + dlds]);                          \
        _Pragma("unroll")                                                            \
        for (int s = 0; s < 4; ++s)                                                  \
            GLOAD(BT + (bbase + s * 64 + srow) * KDIM + (kb) + skoff,                \
                  &Bs[(db) * (BN * BK) + s * 4096 + dlds]);                          \
    } while (0)

    constexpr int NKT = KDIM / BK;

    for (int rt = slot; rt * BM < cnt; rt += NSLOT) {
        const int rowbase = offs[e] + rt * BM;

        __syncthreads();   // prior rt readers done before restaging buffer 0
        STAGE(0, 0);
        __syncthreads();   // drains vmcnt(0): tile 0 resident

        f32x4 acc[8][4];
        #pragma unroll
        for (int m = 0; m < 8; ++m)
            #pragma unroll
            for (int n = 0; n < 4; ++n)
                acc[m][n] = (f32x4){0.f, 0.f, 0.f, 0.f};

        for (int kt = 0; kt < NKT; ++kt) {
            if (kt + 1 < NKT) STAGE((kt + 1) & 1, (kt + 1) * BK);

            const short* asl = &As[(kt & 1) * (BM * BK)];
            const short* bsl = &Bs[(kt & 1) * (BN * BK)];

            {   // half 1: ks0
                bf16x8 a[8], b[4];
                #pragma unroll
                for (int m = 0; m < 8; ++m) a[m] = *(const bf16x8*)&asl[aoff[m]];
                #pragma unroll
                for (int n = 0; n < 4; ++n) b[n] = *(const bf16x8*)&bsl[boff[n]];
                __builtin_amdgcn_s_setprio(1);
                #pragma unroll
                for (int m = 0; m < 8; ++m)
                    #pragma unroll
                    for (int n = 0; n < 4; ++n)
                        acc[m][n] = __builtin_amdgcn_mfma_f32_16x16x32_bf16(a[m], b[n], acc[m][n], 0, 0, 0);
                __builtin_amdgcn_s_setprio(0);
            }
            {   // half 2: ks1
                bf16x8 a[8], b[4];
                #pragma unroll
                for (int m = 0; m < 8; ++m) a[m] = *(const bf16x8*)&asl[aoff[m] ^ 32];
                #pragma unroll
                for (int n = 0; n < 4; ++n) b[n] = *(const bf16x8*)&bsl[boff[n] ^ 32];
                __builtin_amdgcn_s_setprio(1);
                #pragma unroll
                for (int m = 0; m < 8; ++m)
                    #pragma unroll
                    for (int n = 0; n < 4; ++n)
                        acc[m][n] = __builtin_amdgcn_mfma_f32_16x16x32_bf16(a[m], b[n], acc[m][n], 0, 0, 0);
                __builtin_amdgcn_s_setprio(0);
            }

            __syncthreads();   // single drain per K-tile; next tile's loads were
                               // issued ~64 MFMAs ago -> latency covered
        }

        const int rmax = cnt - rt * BM;   // valid rows in this tile (tail tiles < BM)

        if (EPI == 1) {
            short* Hb = (short*)outp;
            #pragma unroll
            for (int n = 0; n < 4; ++n) {
                int col = colbase + wc + n * 16 + l15;
                float bv = bias[e * NDIM + col];
                #pragma unroll
                for (int m = 0; m < 8; ++m) {
                    int r0l = wr + m * 16 + l4 * 4;
                    #pragma unroll
                    for (int r = 0; r < 4; ++r) {
                        int rl = r0l + r;
                        if (rl < rmax) {   // guard: do NOT clobber next expert's rows
                            float vv = acc[m][n][r] + bv;
                            vv = 0.5f * vv * (1.0f + erff(vv * 0.70710678118654752f));
                            Hb[(size_t)(rowbase + rl) * NDIM + col] = (short)f2bf(vv);
                        }
                    }
                }
            }
        } else {
            float* Op = (float*)outp;      // grouped-row order (coalesced tiles)
            #pragma unroll
            for (int n = 0; n < 4; ++n) {
                int col = colbase + wc + n * 16 + l15;
                float bv = bias[e * NDIM + col];
                #pragma unroll
                for (int m = 0; m < 8; ++m) {
                    int r0l = wr + m * 16 + l4 * 4;
                    #pragma unroll
                    for (int r = 0; r < 4; ++r) {
                        int rl = r0l + r;
                        if (rl < rmax)
                            Op[(size_t)(rowbase + rl) * NDIM + col] = acc[m][n][r] + bv;
                    }
                }
            }
        }
    }
#undef STAGE
}

// ---------------- residual + LN + weighted top-k combine (Op in grouped order)
__device__ inline float block_sum256(float v, volatile float* red, int tid)
{
    #pragma unroll
    for (int o = 32; o > 0; o >>= 1) v += __shfl_xor(v, o, 64);
    __syncthreads();
    if ((tid & 63) == 0) red[tid >> 6] = v;
    __syncthreads();
    return red[0] + red[1] + red[2] + red[3];
}

__global__ __launch_bounds__(256) void ln_combine_kernel(
    const float* __restrict__ Op, const float* __restrict__ x,
    const int* __restrict__ topk_i, const float* __restrict__ topk_w,
    const int* __restrict__ inv_row,
    const float* __restrict__ ln_g, const float* __restrict__ ln_b,
    float* __restrict__ y)
{
    __shared__ float red[4];
    const int t = blockIdx.x, tid = threadIdx.x;
    const float4 xr = *(const float4*)&x[(size_t)t * HD + tid * 4];
    float a0 = 0.f, a1 = 0.f, a2 = 0.f, a3 = 0.f;
    #pragma unroll
    for (int k = 0; k < TOPK; ++k) {
        int e = topk_i[t * 2 + k];
        float w = topk_w[t * 2 + k];
        int grow = inv_row[t * 2 + k];
        const float4 o = *(const float4*)&Op[(size_t)grow * HD + tid * 4];
        float v0 = o.x + xr.x, v1 = o.y + xr.y, v2 = o.z + xr.z, v3 = o.w + xr.w;
        float s = block_sum256(v0 + v1 + v2 + v3, red, tid);
        float m = s * (1.0f / HD);
        float d0 = v0 - m, d1 = v1 - m, d2 = v2 - m, d3 = v3 - m;
        float ssq = block_sum256(d0 * d0 + d1 * d1 + d2 * d2 + d3 * d3, red, tid);
        float inv = 1.0f / sqrtf(ssq * (1.0f / HD) + 1e-5f);
        int base = e * HD + tid * 4;
        const float4 g = *(const float4*)&ln_g[base];
        const float4 bb = *(const float4*)&ln_b[base];
        a0 += w * (d0 * inv * g.x + bb.x);
        a1 += w * (d1 * inv * g.y + bb.y);
        a2 += w * (d2 * inv * g.z + bb.z);
        a3 += w * (d3 * inv * g.w + bb.w);
    }
    *(float4*)&y[(size_t)t * HD + tid * 4] = make_float4(a0, a1, a2, a3);
}

__global__ void zero_out_kernel(float* __restrict__ y, int n)
{
    int i = blockIdx.x * 256 + threadIdx.x;
    if (i < n) y[i] = 0.f;
}

extern "C" void kernel_launch(void* const* d_in, const int* in_sizes, int n_in,
                              void* d_out, int out_size, void* d_ws, size_t ws_size,
                              hipStream_t stream)
{
    const float* x      = (const float*)d_in[0];
    const float* W1     = (const float*)d_in[1];
    const float* b1     = (const float*)d_in[2];
    const float* W2     = (const float*)d_in[3];
    const float* b2     = (const float*)d_in[4];
    const float* ln_g   = (const float*)d_in[5];
    const float* ln_b   = (const float*)d_in[6];
    const float* gn_g   = (const float*)d_in[7];
    const float* gn_b   = (const float*)d_in[8];
    const float* gate_w = (const float*)d_in[9];
    const float* gate_b = (const float*)d_in[10];
    float* y = (float*)d_out;

    char* ws = (char*)d_ws;
    size_t off = 0;
    auto take = [&](size_t b) -> char* {
        char* p = ws + off;
        off = (off + b + 255) & ~(size_t)255;
        return p;
    };
    short* W1T     = (short*)take((size_t)NE * FD * HD * 2);       // [E][F][H] bf16
    short* W2T     = (short*)take((size_t)NE * HD * FD * 2);       // [E][H][F] bf16
    short* Xg      = (short*)take((size_t)(NPAIR + PADR) * HD * 2);
    short* Hb      = (short*)take((size_t)(NPAIR + PADR) * FD * 2);
    float* Op      = (float*)take((size_t)NPAIR * HD * 4);         // grouped rows
    int*   topk_i  = (int*)take(NPAIR * 4);
    float* topk_w  = (float*)take(NPAIR * 4);
    int*   cnts    = (int*)take(64);            // 8 counts + 8 cursor
    int*   cursor  = cnts + 8;
    int*   offs    = (int*)take(64);
    int*   pair_tok= (int*)take((size_t)(NPAIR + PADR) * 4);
    int*   inv_row = (int*)take((size_t)NPAIR * 4);

    if (ws_size < off) {   // workspace too small: emit zeros so failure mode is diagnosable
        zero_out_kernel<<<(out_size + 255) / 256, 256, 0, stream>>>(y, out_size);
        return;
    }

    hipMemsetAsync(cnts, 0, 64, stream);

    transpose_cvt_kernel<HD, FD><<<dim3(FD / 64, HD / 64, NE), 256, 0, stream>>>(W1, W1T);
    transpose_cvt_kernel<FD, HD><<<dim3(HD / 64, FD / 64, NE), 256, 0, stream>>>(W2, W2T);

    gating_kernel<<<TOK / 4, 256, 0, stream>>>(x, gn_g, gn_b, gate_w, gate_b, topk_i, topk_w, cnts);
    offsets_kernel<<<1, 64, 0, stream>>>(cnts, offs);
    scatter_kernel<<<NPAIR / 256, 256, 0, stream>>>(topk_i, offs, cursor, pair_tok, inv_row);
    gather_kernel<<<NPAIR, 256, 0, stream>>>(x, pair_tok, Xg);

    // GEMM1: [pairs x HD] @ W1T -> gelu -> Hb   (16 col tiles x 64 (e,slot))
    gemm_kernel<HD, FD, 1><<<dim3(FD / BN, NE * NSLOT), 512, 0, stream>>>(
        Xg, W1T, b1, (void*)Hb, cnts, offs);
    // GEMM2: [pairs x FD] @ W2T -> +b2 -> Op (grouped)   (4 col tiles x 64)
    gemm_kernel<FD, HD, 2><<<dim3(HD / BN, NE * NSLOT), 512, 0, stream>>>(
        Hb, W2T, b2, (void*)Op, cnts, offs);

    ln_combine_kernel<<<TOK, 256, 0, stream>>>(Op, x, topk_i, topk_w, inv_row, ln_g, ln_b, y);
}